// Round 5
// baseline (153.073 us; speedup 1.0000x reference)
//
#include <hip/hip_runtime.h>

// Round 5 = round 4 resubmitted verbatim: the round-4 bench died in container
// acquisition ("MI355X container failed twice"), no kernel verdict was produced.

#define KK 27
#define PT 14   // packed taps per phase (27 taps -> 14 pairs, last half dummy)

typedef short bf16x8 __attribute__((ext_vector_type(8)));   // 8 bf16 in 4 VGPRs
typedef float f32x4  __attribute__((ext_vector_type(4)));

__device__ inline unsigned short f2bf(float f) {            // RNE fp32 -> bf16
    unsigned u = __float_as_uint(f);
    unsigned r = u + 0x7fffu + ((u >> 16) & 1u);
    return (unsigned short)(r >> 16);
}

// ---- Kernel 1 (fused prep) ----
// blocks [0,nxblk): x [32][N] fp32 -> xLo[N+1][16] (cin 0..15), xHi[N+1][16] (cin 16..31) bf16.
//   Row N of each half is all-zero (gathered by out-of-range/dummy lanes).
// blocks [nxblk, nxblk+PT): packed weights. wP0[t][cout=32][k32=32] where
//   k32<16 -> tap 2t, cin=k32 ; k32>=16 -> tap 2t+1, cin=k32-16 (wP1: cin+16).
//   tap 27 (t=13 upper half) is zero-filled.
// block nxblk (t==0) also zeroes the striped BN accumulator tot[32*64].
__global__ __launch_bounds__(256) void prep_k(const float* __restrict__ in,
                                              const float* __restrict__ w,
                                              unsigned short* __restrict__ xLo,
                                              unsigned short* __restrict__ xHi,
                                              unsigned short* __restrict__ wP0,
                                              unsigned short* __restrict__ wP1,
                                              float* __restrict__ tot,
                                              int N, int nxblk) {
    __shared__ float tile[32][33];
    const int b = blockIdx.x;
    if (b < nxblk) {
        int n0 = b * 32;
        int tx = threadIdx.x & 31;   // channel on write side
        int ty = threadIdx.x >> 5;   // 0..7
#pragma unroll
        for (int c = ty; c < 32; c += 8) {
            int n = n0 + tx;
            tile[c][tx] = (n < N) ? in[(long)c * N + n] : 0.f;
        }
        __syncthreads();
#pragma unroll
        for (int nn = ty; nn < 32; nn += 8) {
            int n = n0 + nn;
            if (n < N) {
                unsigned short v = f2bf(tile[tx][nn]);
                if (tx < 16) xLo[(long)n * 16 + tx]        = v;
                else         xHi[(long)n * 16 + (tx - 16)] = v;
            }
        }
        if (b == 0 && threadIdx.x < 32) {   // zero rows at index N
            int t = threadIdx.x;
            if (t < 16) xLo[(long)N * 16 + t]        = 0;
            else        xHi[(long)N * 16 + (t - 16)] = 0;
        }
    } else {
        int t = b - nxblk;                  // 0..PT-1
        for (int i = threadIdx.x; i < 1024; i += 256) {
            int cout = i >> 5, k32 = i & 31;
            int tap = 2 * t + (k32 >> 4);
            int c   = k32 & 15;
            unsigned short lo = 0, hi = 0;
            if (tap < KK) {
                lo = f2bf(w[tap * 1024 + c * 32 + cout]);
                hi = f2bf(w[tap * 1024 + (c + 16) * 32 + cout]);
            }
            wP0[t * 1024 + cout * 32 + k32] = lo;
            wP1[t * 1024 + cout * 32 + k32] = hi;
        }
        if (t == 0) {
            for (int i = threadIdx.x; i < 32 * 64; i += 256) tot[i] = 0.f;
        }
    }
}

// ---- Kernel 2: MFMA conv, cin-split two-phase for L2 residency ----
// 1 wave per 32 nodes (round-0 skeleton: 2 gather streams, depth-2 pipeline).
// Phase ph gathers ONLY x{Lo,Hi} (3.2MB each -> L2-resident per XCD); acc persists.
// Packed tap t: quads 0,1 -> tap 2t; quads 2,3 -> tap 2t+1 (per-lane neighbor index).
// neigh loads and y stores are nontemporal so streaming traffic doesn't evict x-half.
__global__ __launch_bounds__(64, 4) void conv_k(const unsigned short* __restrict__ xLo,
                                                const unsigned short* __restrict__ xHi,
                                                const int* __restrict__ neigh,
                                                const unsigned short* __restrict__ wP0,
                                                const unsigned short* __restrict__ wP1,
                                                float* __restrict__ y,    // [32][N]
                                                float* __restrict__ tot,  // [32][64] striped
                                                int N) {
    __shared__ float ct[32][33];

    const int L    = threadIdx.x;      // 0..63
    const int r16  = L & 15;
    const int quad = L >> 4;           // 0..3
    const int tapsel = quad >> 1;      // 0: tap 2t, 1: tap 2t+1
    const int off8   = (quad & 1) * 8; // element offset within 16-elem row
    const int base = blockIdx.x * 32;
    const int n0 = base + r16;
    const int n1 = base + 16 + r16;
    const bool v0 = (n0 < N), v1 = (n1 < N);
    const long nb0 = (long)(v0 ? n0 : 0) * KK;
    const long nb1 = (long)(v1 ? n1 : 0) * KK;

    f32x4 acc00 = {0.f, 0.f, 0.f, 0.f};
    f32x4 acc01 = acc00, acc10 = acc00, acc11 = acc00;

    // per-lane neighbor index for packed-tap target kq; clamped address, dummy -> N
    auto ldidx = [&](long nb, bool v, int kq) -> int {
        int kc = (kq < KK) ? kq : (KK - 1);
        int j  = __builtin_nontemporal_load(neigh + nb + kc);
        return (v && kq < KK) ? j : N;
    };

#pragma unroll 1
    for (int ph = 0; ph < 2; ++ph) {
        const unsigned short* __restrict__ xp = ph ? xHi : xLo;
        const unsigned short* __restrict__ wp = ph ? wP1 : wP0;

        int ia = ldidx(nb0, v0, tapsel);           // packed tap 0
        int ib = ldidx(nb1, v1, tapsel);
        int ja = ldidx(nb0, v0, 2 + tapsel);       // packed tap 1
        int jb = ldidx(nb1, v1, 2 + tapsel);

        bf16x8 a0 = *(const bf16x8*)(xp + (long)ia * 16 + off8);
        bf16x8 a1 = *(const bf16x8*)(xp + (long)ib * 16 + off8);
        bf16x8 b0 = *(const bf16x8*)(wp + r16 * 32 + quad * 8);
        bf16x8 b1 = *(const bf16x8*)(wp + (16 + r16) * 32 + quad * 8);

#pragma unroll 1
        for (int t = 0; t < PT; ++t) {
            bf16x8 na0, na1, pb0, pb1;
            if (t < PT - 1) {
                na0 = *(const bf16x8*)(xp + (long)ja * 16 + off8);
                na1 = *(const bf16x8*)(xp + (long)jb * 16 + off8);
                const unsigned short* wn = wp + (t + 1) * 1024;
                pb0 = *(const bf16x8*)(wn + r16 * 32 + quad * 8);
                pb1 = *(const bf16x8*)(wn + (16 + r16) * 32 + quad * 8);
                ja = ldidx(nb0, v0, 2 * (t + 2) + tapsel);
                jb = ldidx(nb1, v1, 2 * (t + 2) + tapsel);
            }

            acc00 = __builtin_amdgcn_mfma_f32_16x16x32_bf16(a0, b0, acc00, 0, 0, 0);
            acc01 = __builtin_amdgcn_mfma_f32_16x16x32_bf16(a0, b1, acc01, 0, 0, 0);
            acc10 = __builtin_amdgcn_mfma_f32_16x16x32_bf16(a1, b0, acc10, 0, 0, 0);
            acc11 = __builtin_amdgcn_mfma_f32_16x16x32_bf16(a1, b1, acc11, 0, 0, 0);

            if (t < PT - 1) {
                a0 = na0;
                a1 = na1;
                b0 = pb0;
                b1 = pb1;
            }
        }
    }

    // BN partials: sum over this wave's 32 nodes.
    // C/D layout: cout = r16 (acc*0) / 16+r16 (acc*1), node = quad*4 + reg (+16 tile).
    float s0 = 0.f, q0 = 0.f, s1 = 0.f, q1 = 0.f;
#pragma unroll
    for (int r = 0; r < 4; ++r) {
        s0 += acc00[r] + acc10[r];
        q0 += acc00[r] * acc00[r] + acc10[r] * acc10[r];
        s1 += acc01[r] + acc11[r];
        q1 += acc01[r] * acc01[r] + acc11[r] * acc11[r];
    }
#pragma unroll
    for (int off = 16; off < 64; off <<= 1) {   // reduce across quads (nodes)
        s0 += __shfl_xor(s0, off, 64);
        q0 += __shfl_xor(q0, off, 64);
        s1 += __shfl_xor(s1, off, 64);
        q1 += __shfl_xor(q1, off, 64);
    }
    const int stripe = blockIdx.x & 31;         // 32-way striping kills contention
    if (L < 16) {
        float* tb = tot + stripe * 64;
        atomicAdd(&tb[L],      s0);
        atomicAdd(&tb[L + 16], s1);
        atomicAdd(&tb[L + 32], q0);
        atomicAdd(&tb[L + 48], q1);
    }

    // LDS transpose -> coalesced nontemporal y stores ([cout][node], 32 contiguous)
#pragma unroll
    for (int r = 0; r < 4; ++r) {
        ct[quad * 4 + r][r16]           = acc00[r];
        ct[quad * 4 + r][16 + r16]      = acc01[r];
        ct[16 + quad * 4 + r][r16]      = acc10[r];
        ct[16 + quad * 4 + r][16 + r16] = acc11[r];
    }
    __syncthreads();
    const int node = L & 31;
    const int half = L >> 5;
    const int gn = base + node;
    if (gn < N) {
#pragma unroll
        for (int i = 0; i < 16; ++i) {
            const int cout = i * 2 + half;
            __builtin_nontemporal_store(ct[node][cout], y + (long)cout * N + gn);
        }
    }
}

// ---- Kernel 3: normalize y in place (stripe-reduce + stats finalize fused) ----
__global__ __launch_bounds__(256) void norm_k(float* __restrict__ y,
                                              const float* __restrict__ tot,
                                              const float* __restrict__ gamma,
                                              const float* __restrict__ beta, int N) {
    const int d = blockIdx.y;
    float sm = 0.f, sq = 0.f;
#pragma unroll
    for (int s = 0; s < 32; ++s) {              // reduce the 32 stripes (L2-hot, 8KB)
        sm += tot[s * 64 + d];
        sq += tot[s * 64 + 32 + d];
    }
    const float mean = sm / (float)N;
    const float var  = sq / (float)N - mean * mean;
    const float sc   = gamma[d] * rsqrtf(var + 1e-3f);
    const float sh   = beta[d] - mean * sc;

    int i = blockIdx.x * blockDim.x + threadIdx.x;
    int base = i * 4;
    if (base + 3 < N) {
        float4* p = (float4*)(y + (long)d * N + base);
        float4 v = *p;
        v.x = fmaf(v.x, sc, sh);
        v.y = fmaf(v.y, sc, sh);
        v.z = fmaf(v.z, sc, sh);
        v.w = fmaf(v.w, sc, sh);
        *p = v;
    } else if (base < N) {
        for (int t = base; t < N; ++t) y[(long)d * N + t] = fmaf(y[(long)d * N + t], sc, sh);
    }
}

// ---- launcher ----
extern "C" void kernel_launch(void* const* d_in, const int* in_sizes, int n_in,
                              void* d_out, int out_size, void* d_ws, size_t ws_size,
                              hipStream_t stream) {
    const float* data_in = (const float*)d_in[0];
    const int*   neigh   = (const int*)d_in[1];
    const float* weight  = (const float*)d_in[2];
    const float* gamma   = (const float*)d_in[3];
    const float* beta    = (const float*)d_in[4];
    float* out = (float*)d_out;

    const int N = in_sizes[1] / KK;
    const int nxblk = (N + 31) / 32;    // x-prep blocks
    const int nblk  = (N + 31) / 32;    // 32 nodes per 1-wave conv block

    char* ws = (char*)d_ws;
    size_t halfBytes = (size_t)(N + 1) * 32;                        // 16 bf16/row
    unsigned short* xLo = (unsigned short*)ws;
    unsigned short* xHi = (unsigned short*)(ws + halfBytes);
    unsigned short* wP0 = (unsigned short*)(ws + 2 * halfBytes);    // PT*1024 bf16
    unsigned short* wP1 = wP0 + PT * 1024;
    float* tot = (float*)((char*)(wP1 + PT * 1024));                // 32*64 floats

    prep_k<<<nxblk + PT, 256, 0, stream>>>(data_in, weight, xLo, xHi, wP0, wP1, tot, N, nxblk);
    conv_k<<<nblk, 64, 0, stream>>>(xLo, xHi, neigh, wP0, wP1, out, tot, N);
    dim3 ngrid(((N + 3) / 4 + 255) / 256, 32);
    norm_k<<<ngrid, 256, 0, stream>>>(out, tot, gamma, beta, N);
}

// Round 6
// 135.706 us; speedup vs baseline: 1.1280x; 1.1280x over previous
//
#include <hip/hip_runtime.h>

#define KK 27

typedef short bf16x8 __attribute__((ext_vector_type(8)));   // 8 bf16 in 4 VGPRs
typedef float f32x4  __attribute__((ext_vector_type(4)));

__device__ inline unsigned short f2bf(float f) {            // RNE fp32 -> bf16
    unsigned u = __float_as_uint(f);
    unsigned r = u + 0x7fffu + ((u >> 16) & 1u);
    return (unsigned short)(r >> 16);
}

// ---- Kernel 1 (fused prep): blocks [0,nxblk) transpose+cast x; blocks [nxblk, nxblk+27) prep W ----
// x [32][N] fp32 -> xTb [N+1][32] bf16 (row N is an all-zero row used by out-of-range lanes)
// weight [27][cin=32][cout=32] fp32 -> wTb [27][cout=32][cin=32] bf16
// block nxblk (k==0) additionally zeroes the striped BN accumulator tot[32*64]
// (safe: conv_k launches after prep_k completes, stream-ordered).
__global__ __launch_bounds__(256) void prep_k(const float* __restrict__ in,
                                              const float* __restrict__ w,
                                              unsigned short* __restrict__ xTb,
                                              unsigned short* __restrict__ wTb,
                                              float* __restrict__ tot,
                                              int N, int nxblk) {
    __shared__ float tile[32][33];
    const int b = blockIdx.x;
    if (b < nxblk) {
        int n0 = b * 32;
        int tx = threadIdx.x & 31;
        int ty = threadIdx.x >> 5;  // 0..7
#pragma unroll
        for (int c = ty; c < 32; c += 8) {
            int n = n0 + tx;
            tile[c][tx] = (n < N) ? in[(long)c * N + n] : 0.f;
        }
        __syncthreads();
#pragma unroll
        for (int nn = ty; nn < 32; nn += 8) {
            int n = n0 + nn;
            if (n < N) xTb[(long)n * 32 + tx] = f2bf(tile[tx][nn]);
        }
        if (b == 0 && threadIdx.x < 32) xTb[(long)N * 32 + threadIdx.x] = 0;  // zero row
    } else {
        int k = b - nxblk;
        for (int i = threadIdx.x; i < 1024; i += 256) {
            int cin = i >> 5, cout = i & 31;
            wTb[k * 1024 + cout * 32 + cin] = f2bf(w[k * 1024 + cin * 32 + cout]);
        }
        if (k == 0) {
            for (int i = threadIdx.x; i < 32 * 64; i += 256) tot[i] = 0.f;
        }
    }
}

// ---- Kernel 2: MFMA conv, 4 gather streams x depth-2 ----
// 1 wave per 32 nodes (R0 skeleton). Tap range split into two streams:
//   A-half: taps 0..13 (14), B-half: taps 14..26 (13).
// x 2 M-tiles (n0/n1) = 4 independent gather chains, each depth-2 prefetch.
// Per iteration ~4 x-gathers + 4 w-loads + 4 idx-loads in flight across 8 MFMAs
// (~2.5-3x the in-flight lines of the depth-2x2-stream R0 loop -> latency-bound speedup).
// All pipeline regs individually named (no runtime-indexed arrays -> no scratch).
// Invalid lanes (node >= N) gather the all-zero row N of xTb.
__global__ __launch_bounds__(64, 4) void conv_k(const unsigned short* __restrict__ xTb,
                                                const int* __restrict__ neigh,
                                                const unsigned short* __restrict__ wTb,
                                                float* __restrict__ y,    // [32][N]
                                                float* __restrict__ tot,  // [32][64] striped
                                                int N) {
    __shared__ float ct[32][33];

    const int L    = threadIdx.x;      // 0..63
    const int r16  = L & 15;
    const int quad = L >> 4;           // 0..3
    const int base = blockIdx.x * 32;
    const int n0 = base + r16;
    const int n1 = base + 16 + r16;
    const bool v0 = (n0 < N), v1 = (n1 < N);
    const long nb0 = (long)(v0 ? n0 : 0) * KK;
    const long nb1 = (long)(v1 ? n1 : 0) * KK;

    f32x4 acc00 = {0.f, 0.f, 0.f, 0.f};
    f32x4 acc01 = acc00, acc10 = acc00, acc11 = acc00;

    // ---- prologue: tap 0 (A) and tap 14 (B) data, next indices for taps 1 / 15 ----
    int iA0 = v0 ? neigh[nb0 + 0]  : N;
    int iA1 = v1 ? neigh[nb1 + 0]  : N;
    int iB0 = v0 ? neigh[nb0 + 14] : N;
    int iB1 = v1 ? neigh[nb1 + 14] : N;

    bf16x8 xA0 = *(const bf16x8*)(xTb + (long)iA0 * 32 + quad * 8);
    bf16x8 xA1 = *(const bf16x8*)(xTb + (long)iA1 * 32 + quad * 8);
    bf16x8 xB0 = *(const bf16x8*)(xTb + (long)iB0 * 32 + quad * 8);
    bf16x8 xB1 = *(const bf16x8*)(xTb + (long)iB1 * 32 + quad * 8);

    bf16x8 wA0 = *(const bf16x8*)(wTb + r16 * 32 + quad * 8);                  // tap 0
    bf16x8 wA1 = *(const bf16x8*)(wTb + (16 + r16) * 32 + quad * 8);
    bf16x8 wB0 = *(const bf16x8*)(wTb + 14 * 1024 + r16 * 32 + quad * 8);      // tap 14
    bf16x8 wB1 = *(const bf16x8*)(wTb + 14 * 1024 + (16 + r16) * 32 + quad * 8);

    iA0 = v0 ? neigh[nb0 + 1]  : N;
    iA1 = v1 ? neigh[nb1 + 1]  : N;
    iB0 = v0 ? neigh[nb0 + 15] : N;
    iB1 = v1 ? neigh[nb1 + 15] : N;

#pragma unroll 1
    for (int i = 0; i < 14; ++i) {
        bf16x8 nxA0, nxA1, nxB0, nxB1, nwA0, nwA1, nwB0, nwB1;
        if (i < 13) {
            // prefetch data for A tap i+1 and B tap 15+i (clamped; tail regs unused)
            nxA0 = *(const bf16x8*)(xTb + (long)iA0 * 32 + quad * 8);
            nxA1 = *(const bf16x8*)(xTb + (long)iA1 * 32 + quad * 8);
            nxB0 = *(const bf16x8*)(xTb + (long)iB0 * 32 + quad * 8);
            nxB1 = *(const bf16x8*)(xTb + (long)iB1 * 32 + quad * 8);
            const unsigned short* wa = wTb + (i + 1) * 1024;
            const int kb = (15 + i <= 26) ? (15 + i) : 26;
            const unsigned short* wb = wTb + kb * 1024;
            nwA0 = *(const bf16x8*)(wa + r16 * 32 + quad * 8);
            nwA1 = *(const bf16x8*)(wa + (16 + r16) * 32 + quad * 8);
            nwB0 = *(const bf16x8*)(wb + r16 * 32 + quad * 8);
            nwB1 = *(const bf16x8*)(wb + (16 + r16) * 32 + quad * 8);
            // indices two taps ahead (clamped; dummy fetches land on real rows, unused)
            const int ka2 = (i + 2 <= 13) ? (i + 2) : 13;
            const int kb2 = (16 + i <= 26) ? (16 + i) : 26;
            iA0 = v0 ? neigh[nb0 + ka2] : N;
            iA1 = v1 ? neigh[nb1 + ka2] : N;
            iB0 = v0 ? neigh[nb0 + kb2] : N;
            iB1 = v1 ? neigh[nb1 + kb2] : N;
        }

        // A-half tap i (always: 14 taps)
        acc00 = __builtin_amdgcn_mfma_f32_16x16x32_bf16(xA0, wA0, acc00, 0, 0, 0);
        acc01 = __builtin_amdgcn_mfma_f32_16x16x32_bf16(xA0, wA1, acc01, 0, 0, 0);
        acc10 = __builtin_amdgcn_mfma_f32_16x16x32_bf16(xA1, wA0, acc10, 0, 0, 0);
        acc11 = __builtin_amdgcn_mfma_f32_16x16x32_bf16(xA1, wA1, acc11, 0, 0, 0);
        if (i < 13) {
            // B-half tap 14+i (13 taps, i=0..12)
            acc00 = __builtin_amdgcn_mfma_f32_16x16x32_bf16(xB0, wB0, acc00, 0, 0, 0);
            acc01 = __builtin_amdgcn_mfma_f32_16x16x32_bf16(xB0, wB1, acc01, 0, 0, 0);
            acc10 = __builtin_amdgcn_mfma_f32_16x16x32_bf16(xB1, wB0, acc10, 0, 0, 0);
            acc11 = __builtin_amdgcn_mfma_f32_16x16x32_bf16(xB1, wB1, acc11, 0, 0, 0);
            // rotate pipeline
            xA0 = nxA0; xA1 = nxA1; xB0 = nxB0; xB1 = nxB1;
            wA0 = nwA0; wA1 = nwA1; wB0 = nwB0; wB1 = nwB1;
        }
    }

    // BN partials: sum over this wave's 32 nodes.
    // C/D layout: cout = r16 (acc*0) / 16+r16 (acc*1), node = quad*4 + reg (+16 tile).
    float s0 = 0.f, q0 = 0.f, s1 = 0.f, q1 = 0.f;
#pragma unroll
    for (int r = 0; r < 4; ++r) {
        s0 += acc00[r] + acc10[r];
        q0 += acc00[r] * acc00[r] + acc10[r] * acc10[r];
        s1 += acc01[r] + acc11[r];
        q1 += acc01[r] * acc01[r] + acc11[r] * acc11[r];
    }
#pragma unroll
    for (int off = 16; off < 64; off <<= 1) {   // reduce across quads (nodes)
        s0 += __shfl_xor(s0, off, 64);
        q0 += __shfl_xor(q0, off, 64);
        s1 += __shfl_xor(s1, off, 64);
        q1 += __shfl_xor(q1, off, 64);
    }
    const int stripe = blockIdx.x & 31;         // 32-way striping kills contention
    if (L < 16) {
        float* tb = tot + stripe * 64;
        atomicAdd(&tb[L],      s0);
        atomicAdd(&tb[L + 16], s1);
        atomicAdd(&tb[L + 32], q0);
        atomicAdd(&tb[L + 48], q1);
    }

    // LDS transpose -> coalesced y stores ([cout][node], 32 contiguous nodes)
#pragma unroll
    for (int r = 0; r < 4; ++r) {
        ct[quad * 4 + r][r16]           = acc00[r];
        ct[quad * 4 + r][16 + r16]      = acc01[r];
        ct[16 + quad * 4 + r][r16]      = acc10[r];
        ct[16 + quad * 4 + r][16 + r16] = acc11[r];
    }
    __syncthreads();
    const int node = L & 31;
    const int half = L >> 5;
    const int gn = base + node;
    if (gn < N) {
#pragma unroll
        for (int i = 0; i < 16; ++i) {
            const int cout = i * 2 + half;
            y[(long)cout * N + gn] = ct[node][cout];
        }
    }
}

// ---- Kernel 3: normalize y in place (stripe-reduce + stats finalize fused) ----
__global__ __launch_bounds__(256) void norm_k(float* __restrict__ y,
                                              const float* __restrict__ tot,
                                              const float* __restrict__ gamma,
                                              const float* __restrict__ beta, int N) {
    const int d = blockIdx.y;
    float sm = 0.f, sq = 0.f;
#pragma unroll
    for (int s = 0; s < 32; ++s) {              // reduce the 32 stripes (L2-hot, 8KB)
        sm += tot[s * 64 + d];
        sq += tot[s * 64 + 32 + d];
    }
    const float mean = sm / (float)N;
    const float var  = sq / (float)N - mean * mean;
    const float sc   = gamma[d] * rsqrtf(var + 1e-3f);
    const float sh   = beta[d] - mean * sc;

    int i = blockIdx.x * blockDim.x + threadIdx.x;
    int base = i * 4;
    if (base + 3 < N) {
        float4* p = (float4*)(y + (long)d * N + base);
        float4 v = *p;
        v.x = fmaf(v.x, sc, sh);
        v.y = fmaf(v.y, sc, sh);
        v.z = fmaf(v.z, sc, sh);
        v.w = fmaf(v.w, sc, sh);
        *p = v;
    } else if (base < N) {
        for (int t = base; t < N; ++t) y[(long)d * N + t] = fmaf(y[(long)d * N + t], sc, sh);
    }
}

// ---- launcher ----
extern "C" void kernel_launch(void* const* d_in, const int* in_sizes, int n_in,
                              void* d_out, int out_size, void* d_ws, size_t ws_size,
                              hipStream_t stream) {
    const float* data_in = (const float*)d_in[0];
    const int*   neigh   = (const int*)d_in[1];
    const float* weight  = (const float*)d_in[2];
    const float* gamma   = (const float*)d_in[3];
    const float* beta    = (const float*)d_in[4];
    float* out = (float*)d_out;

    const int N = in_sizes[1] / KK;
    const int nxblk = (N + 31) / 32;    // x-prep blocks
    const int nblk  = (N + 31) / 32;    // 32 nodes per 1-wave conv block

    char* ws = (char*)d_ws;
    unsigned short* xTb = (unsigned short*)ws;                            // (N+1)*32 bf16
    unsigned short* wTb = (unsigned short*)(ws + (size_t)(N + 1) * 64);   // 27*1024 bf16
    float* tot = (float*)(ws + (size_t)(N + 1) * 64 + 55296);             // 32*64 floats

    prep_k<<<nxblk + KK, 256, 0, stream>>>(data_in, weight, xTb, wTb, tot, N, nxblk);
    conv_k<<<nblk, 64, 0, stream>>>(xTb, neigh, wTb, out, tot, N);
    dim3 ngrid(((N + 3) / 4 + 255) / 256, 32);
    norm_k<<<ngrid, 256, 0, stream>>>(out, tot, gamma, beta, N);
}